// Round 5
// baseline (397.575 us; speedup 1.0000x reference)
//
#include <hip/hip_runtime.h>
#include <math.h>

#define HW 64

typedef unsigned long long u64;

// f32 fast-raster record: 16 floats = 64 B, read as 4 float4 vector loads
// q0={wx0,wy0,wc0,wx1} q1={wy1,wc1,wx2,wy2} q2={wc2,z0,z1,z2} q3={epsf,epsz,-,-}
struct FaceRasF {
  float wx0, wy0, wc0;
  float wx1, wy1, wc1;
  float wx2, wy2, wc2;
  float z0, z1, z2;
  float epsf, epsz;
  float pad0, pad1;
};

// exact-geometry record: f32 image coords + camera z (the reference's f32 inputs
// to the f64 rasterization). 12 floats = 48 B = 3 float4.
// g0={v0x,v0y,v1x,v1y} g1={v2x,v2y,z0,z1} g2={z2,-,-,-}
struct FaceGeo {
  float v0x, v0y, v1x, v1y;
  float v2x, v2y, z0, z1;
  float z2, pad0, pad1, pad2;
};

// launder an index through a VGPR so the compiler cannot scalarize the
// subsequent address math -> forces global_load_dwordx4 (deep vmcnt queue,
// ordered returns) instead of s_load chains (unordered -> lgkmcnt(0) drain).
__device__ __forceinline__ int vlaunder(int x) {
  int y;
  asm volatile("v_mov_b32 %0, %1" : "=v"(y) : "v"(x));
  return y;
}

__global__ void k_zero(float* __restrict__ vnorm, int nvn,
                       u64* __restrict__ rowmask, int maskwords,
                       int* __restrict__ cnt) {
  int i = blockIdx.x * blockDim.x + threadIdx.x;
  int total = gridDim.x * blockDim.x;
  for (int j = i; j < nvn; j += total) vnorm[j] = 0.f;
  for (int j = i; j < maskwords; j += total) rowmask[j] = 0ull;
  if (i == 0) cnt[0] = 0;
}

__global__ void k_facepre(const float* __restrict__ vert,
                          const float* __restrict__ rot,
                          const float* __restrict__ trans,
                          const int* __restrict__ faces,
                          FaceRasF* __restrict__ frasF,
                          FaceGeo* __restrict__ fgeo,
                          u64* __restrict__ rowmask, int WPR,
                          float* __restrict__ vnorm,
                          int B, int V, int F) {
  int i = blockIdx.x * blockDim.x + threadIdx.x;
  if (i >= B * F) return;
  int b = i / F, f = i % F;
  const float* R = rot + b * 9;
  const float* t = trans + b * 3;
  int vid[3] = {faces[f * 3 + 0], faces[f * 3 + 1], faces[f * 3 + 2]};
  float cx[3], cy[3], cz[3];
#pragma unroll
  for (int k = 0; k < 3; ++k) {   // inline camera transform (same f32 ordering as ref)
    const float* vv = vert + (size_t)(b * V + vid[k]) * 3;
    float x = vv[0], y = vv[1], z = vv[2];
    cx[k] = ((x * R[0] + y * R[1]) + z * R[2]) + t[0];
    cy[k] = ((x * R[3] + y * R[4]) + z * R[5]) + t[1];
    cz[k] = ((x * R[6] + y * R[7]) + z * R[8]) + t[2];
  }
  float c0z = cz[0], c1z = cz[1], c2z = cz[2];
  // f32 image coords (matches reference vs_img = xy/z in f32)
  float v0x = cx[0] / c0z, v0y = cy[0] / c0z;
  float v1x = cx[1] / c1z, v1y = cy[1] / c1z;
  float v2x = cx[2] / c2z, v2y = cy[2] / c2z;
  FaceGeo ge;
  ge.v0x = v0x; ge.v0y = v0y; ge.v1x = v1x; ge.v1y = v1y;
  ge.v2x = v2x; ge.v2y = v2y; ge.z0 = c0z; ge.z1 = c1z;
  ge.z2 = c2z; ge.pad0 = 0.f; ge.pad1 = 0.f; ge.pad2 = 0.f;
  fgeo[i] = ge;
  // f32 edge deltas (reference computes these in f32 before f64 promotion)
  float dx0 = v2x - v1x, dy0 = v2y - v1y;   // edge(v1,v2), anchor v1
  float dx1 = v0x - v2x, dy1 = v0y - v2y;   // edge(v2,v0), anchor v2
  float dx2 = v1x - v0x, dy2 = v1y - v0y;   // edge(v0,v1), anchor v0
  float A = dx2 * (v2y - v0y) - dy2 * (v2x - v0x);
  if (fabsf(A) < 1e-8f) A = 1e-8f;
  double invA = 1.0 / (double)A;
  // premultiplied barycentric coefficients: w_e = wx*px + wy*py + wc
  double wx0 = -(double)dy0 * invA, wy0 = (double)dx0 * invA;
  double wc0 = ((double)dy0 * (double)v1x - (double)dx0 * (double)v1y) * invA;
  double wx1 = -(double)dy1 * invA, wy1 = (double)dx1 * invA;
  double wc1 = ((double)dy1 * (double)v2x - (double)dx1 * (double)v2y) * invA;
  double wx2 = -(double)dy2 * invA, wy2 = (double)dx2 * invA;
  double wc2 = ((double)dy2 * (double)v0x - (double)dx2 * (double)v0y) * invA;
  double m0 = fabs(wx0) + fabs(wy0) + fabs(wc0);
  double m1 = fabs(wx1) + fabs(wy1) + fabs(wc1);
  double m2 = fabs(wx2) + fabs(wy2) + fabs(wc2);
  double mm = fmax(fmax(m0, m1), m2);
  float epsf = fmaxf((float)(6e-7 * mm), 3e-7f);  // margin over f32 eval+coeff error
  float zs = fabsf(c0z) + fabsf(c1z) + fabsf(c2z);
  float epsz = (epsf + 4e-6f) * zs;
  FaceRasF fr;
  fr.wx0 = (float)wx0; fr.wy0 = (float)wy0; fr.wc0 = (float)wc0;
  fr.wx1 = (float)wx1; fr.wy1 = (float)wy1; fr.wc1 = (float)wc1;
  fr.wx2 = (float)wx2; fr.wy2 = (float)wy2; fr.wc2 = (float)wc2;
  fr.z0 = c0z; fr.z1 = c1z; fr.z2 = c2z;
  fr.epsf = epsf; fr.epsz = epsz; fr.pad0 = 0.f; fr.pad1 = 0.f;
  frasF[i] = fr;
  // conservative y-row interval of the band-dilated triangle (superset of all
  // faces that can be f64-inside OR contribute prob on the row)
  float band = fmaxf(0.302f, 1.5f * epsf);
  float ylo = -1.01f, yhi = 1.01f;
  bool empty = false;
  float wyA[3] = {fr.wy0, fr.wy1, fr.wy2};
  float gA[3]  = {fr.wc0 + fabsf(fr.wx0) + band,
                  fr.wc1 + fabsf(fr.wx1) + band,
                  fr.wc2 + fabsf(fr.wx2) + band};
#pragma unroll
  for (int e = 0; e < 3; ++e) {
    float wy = wyA[e], g = gA[e];
    if (wy > 1e-30f)       ylo = fmaxf(ylo, -g / wy);
    else if (wy < -1e-30f) yhi = fminf(yhi, -g / wy);
    else                   empty |= (g < 0.f);
    empty |= (g + fabsf(wy) < 0.f);
  }
  if (!empty && ylo <= yhi) {
    int r0 = max(0, (int)floorf((ylo + 1.0f) * 31.5f) - 1);
    int r1 = min(63, (int)ceilf((yhi + 1.0f) * 31.5f) + 1);
    u64 bit = 1ull << (f & 63);
    int word = f >> 6;
    for (int r = r0; r <= r1; ++r)
      atomicOr(&rowmask[((size_t)(b * 64 + r)) * WPR + word], bit);
  }
  // face normal -> vertex normal scatter (f32 atomics)
  float e1x = cx[1] - cx[0], e1y = cy[1] - cy[0], e1z = cz[1] - cz[0];
  float e2x = cx[2] - cx[0], e2y = cy[2] - cy[0], e2z = cz[2] - cz[0];
  float nx = e1y * e2z - e1z * e2y;
  float ny = e1z * e2x - e1x * e2z;
  float nz = e1x * e2y - e1y * e2x;
#pragma unroll
  for (int k = 0; k < 3; ++k) {
    float* vn = vnorm + (size_t)(b * V + vid[k]) * 3;
    atomicAdd(vn + 0, nx); atomicAdd(vn + 1, ny); atomicAdd(vn + 2, nz);
  }
}

// bitmask-driven f32 screened raster; vector-loaded face records,
// depth-2 software pipeline (load face k+1 while computing face k)
__global__ __launch_bounds__(256) void k_raster(
    const FaceRasF* __restrict__ frasF,
    const u64* __restrict__ rowmask, int WPR, int chunkW,
    float4* __restrict__ ppart, int F, int P) {
  int b = blockIdx.x >> 4;
  int rowbase = (blockIdx.x & 15) * 4;
  int wid = __builtin_amdgcn_readfirstlane(threadIdx.x >> 6);
  int row = rowbase + wid;                       // wave-uniform
  int x = threadIdx.x & 63;
  int chunk = blockIdx.y;
  const double step = 2.0 / 63.0;
  double pxd = (x == HW - 1) ? 1.0 : (x * step - 1.0);
  double pyd = (row == HW - 1) ? 1.0 : (row * step - 1.0);
  float pxf = (float)pxd, pyf = (float)pyd;
  const float4* __restrict__ fb4 = (const float4*)(frasF + (size_t)b * F);
  const u64* __restrict__ rm = rowmask + ((size_t)(b * 64 + row)) * WPR + chunk * chunkW;
  int wleft = min(chunkW, WPR - chunk * chunkW);
  float zminf = INFINITY;
  float weps = 0.f;
  int best = 0;
  bool flag = false;
  float lsum = 0.f;

  u64 m = 0;
  int j = -1, fbase = 0;
  auto next_f = [&]() -> int {
    while (m == 0) {
      if (++j >= wleft) return -1;
      m = rm[j];
      fbase = ((chunk * chunkW + j) << 6);
    }
    int bit = __builtin_ctzll(m);
    m &= m - 1;
    return fbase + bit;
  };

  int fc = next_f();
  float4 a0, a1, a2, a3;
  if (fc >= 0) {
    const float4* pf = fb4 + ((size_t)vlaunder(fc) << 2);
    a0 = pf[0]; a1 = pf[1]; a2 = pf[2]; a3 = pf[3];
  }
  while (fc >= 0) {
    int fn = next_f();
    float4 b0, b1, b2, b3;
    if (fn >= 0) {
      const float4* pf = fb4 + ((size_t)vlaunder(fn) << 2);
      b0 = pf[0]; b1 = pf[1]; b2 = pf[2]; b3 = pf[3];
    }
    // compute on current face fc
    float w0 = fmaf(a0.x, pxf, fmaf(a0.y, pyf, a0.z));
    float w1 = fmaf(a0.w, pxf, fmaf(a1.x, pyf, a1.y));
    float w2 = fmaf(a1.z, pxf, fmaf(a1.w, pyf, a2.x));
    float dmin = fminf(fminf(w0, w1), w2);
    if (dmin > -0.3f) {
      // clip(dmin/sigma,-30,0): dmin<=-0.3 contributes ~1e-13, skipped
      float tt = fminf(fmaxf(dmin * 100.0f, -30.0f), 0.0f);
      float pr = __expf(tt);                    // inside -> tt=0 -> pr=1 exactly
      lsum += __logf(fmaf(-pr, 0.99999990f, 1.0f));
    }
    float epsf = a3.x, epsz = a3.y;
    if (dmin > -epsf) {
      float z = fmaf(w2, a2.w, fmaf(w1, a2.z, w0 * a2.y));
      bool contend = (z < zminf + epsz + weps) & (z > -epsz);
      flag |= (fabsf(dmin) < epsf) & contend;             // inside-sign ambiguous
      flag |= (dmin >= 0.0f) & (fabsf(z) < epsz);         // z>0 boundary ambiguous
      flag |= (dmin >= 0.0f) & (z > 0.0f) &
              (fabsf(z - zminf) < epsz + weps);           // z-order ambiguous
      if ((dmin >= 0.0f) & (z > 0.0f) & (z < zminf)) {    // strict <: first-occurrence
        zminf = z; best = fc; weps = epsz;
      }
    }
    fc = fn; a0 = b0; a1 = b1; a2 = b2; a3 = b3;
  }
  int p = b * (HW * HW) + row * HW + x;
  unsigned bestflag = (unsigned)best | (flag ? 0x80000000u : 0u);
  ppart[(size_t)chunk * P + p] =
      make_float4(zminf, __uint_as_float(bestflag), lsum, weps);
}

// exact f64 winner recompute + gather-interpolate + output write (not improb)
__device__ void write_winner(const FaceGeo* __restrict__ fgeo,
                             const int* __restrict__ faces,
                             const float* __restrict__ vnorm,
                             const float* __restrict__ attribs,
                             float* __restrict__ out, int P,
                             int b, int V, int F, int pix,
                             int best, bool covered) {
  int p = b * (HW * HW) + pix;
  float imn[3] = {0.f, 0.f, 0.f};
  float ima[3] = {0.f, 0.f, 0.f};
  if (covered) {
    int x = pix & 63, y = pix >> 6;
    const double step = 2.0 / 63.0;
    double px = (x == HW - 1) ? 1.0 : (x * step - 1.0);
    double py = (y == HW - 1) ? 1.0 : (y * step - 1.0);
    FaceGeo g = fgeo[(size_t)b * F + best];
    float dx0 = g.v2x - g.v1x, dy0 = g.v2y - g.v1y;
    float dx1 = g.v0x - g.v2x, dy1 = g.v0y - g.v2y;
    float dx2 = g.v1x - g.v0x, dy2 = g.v1y - g.v0y;
    float A = dx2 * (g.v2y - g.v0y) - dy2 * (g.v2x - g.v0x);
    if (fabsf(A) < 1e-8f) A = 1e-8f;
    double invA = 1.0 / (double)A;
    double a0 = (double)dx0 * (py - (double)g.v1y) - (double)dy0 * (px - (double)g.v1x);
    double a1 = (double)dx1 * (py - (double)g.v2y) - (double)dy1 * (px - (double)g.v2x);
    double a2 = (double)dx2 * (py - (double)g.v0y) - (double)dy2 * (px - (double)g.v0x);
    double wk[3] = {a0 * invA, a1 * invA, a2 * invA};
    int vid[3] = {faces[best * 3 + 0], faces[best * 3 + 1], faces[best * 3 + 2]};
    double v[6] = {0, 0, 0, 0, 0, 0};
#pragma unroll
    for (int k = 0; k < 3; ++k) {
      const float* n = vnorm + (size_t)(b * V + vid[k]) * 3;
      float nx = n[0], ny = n[1], nz = n[2];
      float nrm = sqrtf(nx * nx + ny * ny + nz * nz) + 1e-10f;  // f32, like ref
      const float* at = attribs + (((size_t)(b * F + best)) * 3 + k) * 3;
      v[0] += wk[k] * (double)(nx / nrm);
      v[1] += wk[k] * (double)(ny / nrm);
      v[2] += wk[k] * (double)(nz / nrm);
      v[3] += wk[k] * (double)at[0];
      v[4] += wk[k] * (double)at[1];
      v[5] += wk[k] * (double)at[2];
    }
    double nn = sqrt(v[0] * v[0] + v[1] * v[1] + v[2] * v[2]) + 1e-10;
    imn[0] = (float)(v[0] / nn);
    imn[1] = (float)(v[1] / nn);
    imn[2] = (float)(v[2] / nn);
    ima[0] = (float)v[3]; ima[1] = (float)v[4]; ima[2] = (float)v[5];
  }
  float* o_n = out;
  float* o_a = out + (size_t)P * 3;
  float* o_p = out + (size_t)P * 6;
  float* o_i = o_p + P;
  o_n[(size_t)p * 3 + 0] = imn[0];
  o_n[(size_t)p * 3 + 1] = imn[1];
  o_n[(size_t)p * 3 + 2] = imn[2];
  o_a[(size_t)p * 3 + 0] = ima[0];
  o_a[(size_t)p * 3 + 1] = ima[1];
  o_a[(size_t)p * 3 + 2] = ima[2];
  o_p[p] = 0.f;   // overwritten by caller for k_final path
  o_i[p] = covered ? (float)best : -1.0f;
}

__global__ __launch_bounds__(256) void k_final(
    const FaceGeo* __restrict__ fgeo,
    const int* __restrict__ faces,
    const float* __restrict__ vnorm,
    const float* __restrict__ attribs,
    const float4* __restrict__ ppart,
    float* __restrict__ out,
    int* __restrict__ cnt, int* __restrict__ list,
    int B, int V, int F, int NC) {
  int p = blockIdx.x * blockDim.x + threadIdx.x;
  int P = B * HW * HW;
  if (p >= P) return;
  float zmin = INFINITY, weps = 0.f, lsum = 0.f;
  int best = 0;
  bool flag = false;
  for (int c = 0; c < NC; ++c) {   // ascending chunks: preserves first-occurrence argmin
    float4 q = ppart[(size_t)c * P + p];
    float z = q.x;
    unsigned pb = __float_as_uint(q.y);
    float e = q.w;
    flag |= (pb >> 31) != 0;
    flag |= fabsf(z - zmin) < (e + weps + 2e-6f);  // cross-chunk near-tie (INF-safe)
    if (z < zmin) { zmin = z; best = (int)(pb & 0x7fffffffu); weps = e; }
    lsum += q.z;
  }
  bool covered = (zmin < 1e38f);
  int b = p >> 12;            // HW*HW = 4096
  int pix = p & 4095;
  write_winner(fgeo, faces, vnorm, attribs, out, P, b, V, F, pix, best, covered);
  float* o_p = out + (size_t)P * 6;
  o_p[p] = 1.0f - __expf(lsum);
  if (flag) {
    int s = atomicAdd(cnt, 1);
    list[s] = p;
  }
}

// exact f64 re-argmin for flagged pixels: one wave per pixel, row-masked faces,
// FaceGeo vector gathers (no faces->vertex chain)
__global__ __launch_bounds__(256) void k_repair(
    const FaceGeo* __restrict__ fgeo,
    const int* __restrict__ faces,
    const float* __restrict__ vnorm,
    const float* __restrict__ attribs,
    const u64* __restrict__ rowmask, int WPR,
    const int* __restrict__ cnt, const int* __restrict__ list,
    float* __restrict__ out, int B, int V, int F) {
  int P = B * HW * HW;
  int lane = threadIdx.x & 63;
  int wid = (blockIdx.x * blockDim.x + threadIdx.x) >> 6;
  int nwaves = (gridDim.x * blockDim.x) >> 6;
  int n = cnt[0];
  int WPL = (WPR + 63) >> 6;   // mask words per lane
  for (int i = wid; i < n; i += nwaves) {
    int p = list[i];
    int b = p >> 12;
    int pix = p & 4095;
    int x = pix & 63, y = pix >> 6;
    const double step = 2.0 / 63.0;
    double px = (x == HW - 1) ? 1.0 : (x * step - 1.0);
    double py = (y == HW - 1) ? 1.0 : (y * step - 1.0);
    const u64* rm = rowmask + ((size_t)(b * 64 + y)) * WPR;
    const float4* g4 = (const float4*)(fgeo + (size_t)b * F);
    double zmin = INFINITY;
    int best = 0x7fffffff;
    for (int k = 0; k < WPL; ++k) {
      int wi = lane * WPL + k;
      if (wi >= WPR) break;
      u64 m = rm[wi];
      while (m) {
        int bit = __builtin_ctzll(m);
        m &= m - 1;
        int f = (wi << 6) + bit;
        const float4* pg = g4 + (size_t)f * 3;
        float4 g0 = pg[0], g1 = pg[1], g2 = pg[2];
        float v0x = g0.x, v0y = g0.y, v1x = g0.z, v1y = g0.w;
        float v2x = g1.x, v2y = g1.y, c0z = g1.z, c1z = g1.w, c2z = g2.x;
        float dx0 = v2x - v1x, dy0 = v2y - v1y;
        float dx1 = v0x - v2x, dy1 = v0y - v2y;
        float dx2 = v1x - v0x, dy2 = v1y - v0y;
        float A = dx2 * (v2y - v0y) - dy2 * (v2x - v0x);
        if (fabsf(A) < 1e-8f) A = 1e-8f;
        double invA = 1.0 / (double)A;
        double a0 = (double)dx0 * (py - (double)v1y) - (double)dy0 * (px - (double)v1x);
        double a1 = (double)dx1 * (py - (double)v2y) - (double)dy1 * (px - (double)v2x);
        double a2 = (double)dx2 * (py - (double)v0y) - (double)dy2 * (px - (double)v0x);
        double w0 = a0 * invA, w1 = a1 * invA, w2 = a2 * invA;
        bool inside = (w0 >= 0.0) & (w1 >= 0.0) & (w2 >= 0.0);
        double z = (w0 * (double)c0z + w1 * (double)c1z) + w2 * (double)c2z;
        // lane-local faces ascend; cross-lane ties resolved in reduce by lower idx
        if (inside & (z > 0.0) & (z < zmin)) { zmin = z; best = f; }
      }
    }
    // lexicographic (z, idx) wave reduce -> first-occurrence argmin
    for (int off = 32; off; off >>= 1) {
      double zo = __shfl_down(zmin, off);
      int bo = __shfl_down(best, off);
      if ((zo < zmin) || ((zo == zmin) && (bo < best))) { zmin = zo; best = bo; }
    }
    if (lane == 0) {
      bool covered = (zmin < 1e300);
      float* o_p = out + (size_t)P * 6;
      float keep = o_p[p];                 // preserve improb (written by k_final)
      write_winner(fgeo, faces, vnorm, attribs, out, P, b, V, F, pix, best, covered);
      o_p[p] = keep;
    }
  }
}

extern "C" void kernel_launch(void* const* d_in, const int* in_sizes, int n_in,
                              void* d_out, int out_size, void* d_ws, size_t ws_size,
                              hipStream_t stream) {
  const float* vert    = (const float*)d_in[0];
  const int*   faces   = (const int*)d_in[1];
  const float* attribs = (const float*)d_in[2];
  const float* rot     = (const float*)d_in[3];
  const float* trans   = (const float*)d_in[4];
  int B = in_sizes[4] / 3;
  int V = in_sizes[0] / (3 * B);
  int F = in_sizes[1] / 3;
  int P = B * HW * HW;
  int WPR = (F + 63) / 64;
  int maskwords = B * 64 * WPR;

  size_t fixedsz = sizeof(FaceRasF) * (size_t)B * F + sizeof(FaceGeo) * (size_t)B * F +
                   8u * (size_t)maskwords + 12u * (size_t)B * V + 4 + 4u * (size_t)P + 512;
  int chunkW = 4;
  while (fixedsz + (size_t)P * 16u * ((WPR + chunkW - 1) / chunkW) > ws_size &&
         chunkW < WPR) chunkW <<= 1;
  int NC = (WPR + chunkW - 1) / chunkW;

  char* w = (char*)d_ws;
  FaceRasF* frasF = (FaceRasF*)w; w += sizeof(FaceRasF) * (size_t)B * F;
  FaceGeo* fgeo   = (FaceGeo*)w;  w += sizeof(FaceGeo) * (size_t)B * F;
  float4* ppart   = (float4*)w;   w += 16u * (size_t)P * NC;
  u64* rowmask    = (u64*)w;      w += 8u * (size_t)maskwords;
  float* vnorm    = (float*)w;    w += sizeof(float) * 3 * (size_t)B * V;
  int* cnt        = (int*)w;      w += sizeof(int);
  int* list       = (int*)w;      w += sizeof(int) * (size_t)P;

  k_zero<<<128, 256, 0, stream>>>(vnorm, B * V * 3, rowmask, maskwords, cnt);
  k_facepre<<<(B * F + 255) / 256, 256, 0, stream>>>(
      vert, rot, trans, faces, frasF, fgeo, rowmask, WPR, vnorm, B, V, F);
  dim3 rg((unsigned)(B * 16), (unsigned)NC);
  k_raster<<<rg, 256, 0, stream>>>(frasF, rowmask, WPR, chunkW, ppart, F, P);
  k_final<<<(P + 255) / 256, 256, 0, stream>>>(fgeo, faces, vnorm, attribs, ppart,
                                               (float*)d_out, cnt, list, B, V, F, NC);
  k_repair<<<128, 256, 0, stream>>>(fgeo, faces, vnorm, attribs, rowmask, WPR,
                                    cnt, list, (float*)d_out, B, V, F);
}